// Round 6
// baseline (2170.034 us; speedup 1.0000x reference)
//
#include <hip/hip_runtime.h>

#define T_STEPS 200
#define BATCH   32
#define HID     1024
#define NWG     256
#define NTHR    512

typedef _Float16 half8 __attribute__((ext_vector_type(8)));
typedef float    f32x4 __attribute__((ext_vector_type(4)));

// Coherent (agent-scope, cache-bypassing) 16B load/store from two relaxed 8B
// atomics. Used ONLY for cross-WG data (h ping-pong, y0m) and flags. No
// fences anywhere -> no buffer_inv / buffer_wbl2.
__device__ __forceinline__ half8 ld_coh16(const _Float16* p) {
    union { unsigned long long u[2]; half8 h; } r;
    const unsigned long long* q = (const unsigned long long*)p;
    r.u[0] = __hip_atomic_load(q,     __ATOMIC_RELAXED, __HIP_MEMORY_SCOPE_AGENT);
    r.u[1] = __hip_atomic_load(q + 1, __ATOMIC_RELAXED, __HIP_MEMORY_SCOPE_AGENT);
    return r.h;
}
__device__ __forceinline__ void st_coh16(_Float16* p, half8 v) {
    union { half8 h; unsigned long long u[2]; } r; r.h = v;
    unsigned long long* q = (unsigned long long*)p;
    __hip_atomic_store(q,     r.u[0], __ATOMIC_RELAXED, __HIP_MEMORY_SCOPE_AGENT);
    __hip_atomic_store(q + 1, r.u[1], __ATOMIC_RELAXED, __HIP_MEMORY_SCOPE_AGENT);
}

__device__ __forceinline__ half8 cvt8(const float* p) {
    f32x4 lo = *(const f32x4*)p;
    f32x4 hi = *(const f32x4*)(p + 4);
    half8 a;
    a[0] = (_Float16)lo[0]; a[1] = (_Float16)lo[1];
    a[2] = (_Float16)lo[2]; a[3] = (_Float16)lo[3];
    a[4] = (_Float16)hi[0]; a[5] = (_Float16)hi[1];
    a[6] = (_Float16)hi[2]; a[7] = (_Float16)hi[3];
    return a;
}

__global__ void init_k(const float* __restrict__ h0,
                       _Float16* __restrict__ h0b, _Float16* __restrict__ h1b,
                       unsigned* __restrict__ flag0, unsigned* __restrict__ flag1) {
    int i = blockIdx.x * blockDim.x + threadIdx.x;
    if (i < BATCH * HID) {
        h0b[i] = (_Float16)h0[i];                 // layer 0 initial h -> slot 0
        h1b[i] = (_Float16)h0[BATCH * HID + i];   // layer 1 initial h -> slot 0
    }
    if (blockIdx.x == 0) {
        if (threadIdx.x < 128)      flag0[threadIdx.x * 32] = 0;
        else if (threadIdx.x < 256) flag1[(threadIdx.x - 128) * 32] = 0;
    }
}

// Self-timed dataflow LSTM: NO global barrier. 256 WGs x 512 threads.
// WGs 0-127: layer 0, WGs 128-255: layer 1. Weights persist in LDS.
// flagX[wgl] = number of completed steps of that WG (own 128B line).
// Producer protocol: coherent h/y stores -> s_waitcnt vmcnt(0) -> flag store.
// Consumer protocol: one lane per producer flag spins until >= target, then
// __syncthreads. Layer 0 step s needs flag0[*]>=s; layer 1 step s needs
// flag0[*]>=s+1 (y0m[s]) and flag1[*]>=s. D=2 h slots are ABA-safe because
// flag>=s+1 proves the writer's peers finished READING the slot being reused.
__global__ __launch_bounds__(NTHR, 2) void lstm_main(
    const float* __restrict__ x, const float* __restrict__ c0,
    const float* __restrict__ Wih, const float* __restrict__ Whh,
    const float* __restrict__ bih, const float* __restrict__ bhh,
    const float* __restrict__ mi, const float* __restrict__ mo,
    float* __restrict__ out,
    _Float16* __restrict__ y0m, _Float16* __restrict__ h0b,
    _Float16* __restrict__ h1b, unsigned* __restrict__ flag0,
    unsigned* __restrict__ flag1)
{
    __shared__ _Float16 W_s[32 * 2048];     // 128 KB
    __shared__ float scr[8][2][16][17];     // per-(kq,m) partial gate tiles
    __shared__ float c_s[BATCH][8];         // persistent cell state (f32)
    __shared__ alignas(16) _Float16 st_h[BATCH][8];  // staged h for wave-7 stores
    __shared__ alignas(16) _Float16 st_y[BATCH][8];  // staged y0*mask (layer 0)
    __shared__ float st_o[BATCH][8];        // staged h for out-stores (layer 1)

    const int bid   = blockIdx.x;
    const int layer = bid >> 7;
    const int wgl   = bid & 127;
    const int tid   = threadIdx.x;

    // ---- one-time: stage this WG's weight slice into LDS (f16, swizzled) ----
    const float* WihL = Wih + (size_t)layer * 4 * HID * HID;
    const float* WhhL = Whh + (size_t)layer * 4 * HID * HID;
    for (int idx = tid; idx < 32 * 2048; idx += NTHR) {
        int r = idx >> 11, k = idx & 2047;             // r: local gate-row
        int grow = (r >> 3) * HID + wgl * 8 + (r & 7); // global row in [4H]
        float v = (k < HID) ? WihL[(size_t)grow * HID + k]
                            : WhhL[(size_t)grow * HID + (k - HID)];
        W_s[idx ^ ((r & 7) << 3)] = (_Float16)v;       // XOR-swizzle (16B granules)
    }

    float bias0 = 0.f, bias1 = 0.f, bias2 = 0.f, bias3 = 0.f;
    int b_ = 0, col_ = 0, gcol = 0;
    if (tid < 256) {
        b_ = tid >> 3; col_ = tid & 7; gcol = wgl * 8 + col_;
        bias0 = bih[layer * 4096 + gcol]           + bhh[layer * 4096 + gcol];
        bias1 = bih[layer * 4096 + HID + gcol]     + bhh[layer * 4096 + HID + gcol];
        bias2 = bih[layer * 4096 + 2 * HID + gcol] + bhh[layer * 4096 + 2 * HID + gcol];
        bias3 = bih[layer * 4096 + 3 * HID + gcol] + bhh[layer * 4096 + 3 * HID + gcol];
        c_s[b_][col_] = c0[((size_t)layer * BATCH + b_) * HID + gcol];
    }
    // out-store / mask threads (waves 4-7): own (b2, c2)
    const int ot = tid - 256;
    const int b2 = (ot >= 0) ? (ot >> 3) : 0, c2 = (ot >= 0) ? (ot & 7) : 0;
    const int gcol2 = wgl * 8 + c2;
    __syncthreads();

    const int lane = tid & 63, wid = tid >> 6;
    // layer 0: waves 0-3 own the h-half (kq 2,3) so pollers/act have no
    // prefetch duties; waves 4-7 own the x-half (kq 0,1, register-prefetched).
    // layer 1: plain kq = wid>>1 (y0m and h1 are both dependent loads).
    int kq;
    if (layer == 0) kq = (wid < 4) ? (2 + (wid >> 1)) : ((wid - 4) >> 1);
    else            kq = wid >> 1;
    const int mm   = wid & 1;
    const int srow = kq * 2 + mm;          // scr slot (logical, not wid)
    const int row = lane & 15, bb = mm * 16 + row, ko = (lane >> 4) * 8;

    // ---- prefetched pure-t state ----
    half8 aF[16];
    float mi_reg = 0.f, mo_reg = 0.f;
    if (layer == 0 && kq < 2) {
        const float* xp = x + (size_t)bb * HID + kq * 512 + ko;   // s = 0
        #pragma unroll
        for (int kk = 0; kk < 16; ++kk) aF[kk] = cvt8(xp + kk * 32);
    }
    if (layer == 1 && ot >= 0) mo_reg = mo[(size_t)b2 * HID + gcol2];  // s = 0

    for (int s = 0; s < T_STEPS; ++s) {
        // ---- dataflow wait (lane-private spins; no pending stores here) ----
        if (layer == 0) {
            if (tid < 128) {
                const unsigned* f = flag0 + tid * 32;
                const unsigned tgt = (unsigned)s;
                while (__hip_atomic_load(f, __ATOMIC_RELAXED,
                                         __HIP_MEMORY_SCOPE_AGENT) < tgt) {}
            }
        } else {
            if (tid < 128) {
                const unsigned* f = flag0 + tid * 32;
                const unsigned tgt = (unsigned)(s + 1);
                while (__hip_atomic_load(f, __ATOMIC_RELAXED,
                                         __HIP_MEMORY_SCOPE_AGENT) < tgt) {}
            } else if (tid < 256) {
                const unsigned* f = flag1 + (tid - 128) * 32;
                const unsigned tgt = (unsigned)s;
                while (__hip_atomic_load(f, __ATOMIC_RELAXED,
                                         __HIP_MEMORY_SCOPE_AGENT) < tgt) {}
            }
        }
        asm volatile("" ::: "memory");
        __syncthreads();

        // ---- mask load for this step (hidden under MFMA phase) ----
        if (layer == 0 && tid < 256)
            mi_reg = mi[((size_t)s * BATCH + b_) * HID + gcol];

        // ---- dependent A fragments ----
        if (layer == 0) {
            if (kq >= 2) {
                const _Float16* hp = h0b + (s & 1) * (BATCH * HID)
                                   + bb * HID + (kq - 2) * 512 + ko;
                #pragma unroll
                for (int kk = 0; kk < 16; ++kk) aF[kk] = ld_coh16(hp + kk * 32);
            }
        } else {
            if (kq < 2) {
                const _Float16* yp = y0m + ((size_t)s * BATCH + bb) * HID + kq * 512 + ko;
                #pragma unroll
                for (int kk = 0; kk < 16; ++kk) aF[kk] = ld_coh16(yp + kk * 32);
            } else {
                const _Float16* hp = h1b + (s & 1) * (BATCH * HID)
                                   + bb * HID + (kq - 2) * 512 + ko;
                #pragma unroll
                for (int kk = 0; kk < 16; ++kk) aF[kk] = ld_coh16(hp + kk * 32);
            }
        }

        // ---- MFMA: D[batch 16][gaterow 16] x2 subtiles over K=512 ----
        f32x4 acc0 = {0.f, 0.f, 0.f, 0.f}, acc1 = {0.f, 0.f, 0.f, 0.f};
        #pragma unroll
        for (int kk = 0; kk < 16; ++kk) {
            const int k  = kq * 512 + kk * 32 + ko;
            const int r1 = 16 + row;
            const half8 bB0 = *(const half8*)&W_s[(row * 2048 + k) ^ ((row & 7) << 3)];
            const half8 bB1 = *(const half8*)&W_s[(r1 * 2048 + k) ^ ((r1 & 7) << 3)];
            acc0 = __builtin_amdgcn_mfma_f32_16x16x32_f16(aF[kk], bB0, acc0, 0, 0, 0);
            acc1 = __builtin_amdgcn_mfma_f32_16x16x32_f16(aF[kk], bB1, acc1, 0, 0, 0);
        }
        #pragma unroll
        for (int j = 0; j < 4; ++j) {
            scr[srow][0][(lane >> 4) * 4 + j][row] = acc0[j];
            scr[srow][1][(lane >> 4) * 4 + j][row] = acc1[j];
        }
        __syncthreads();

        // ---- activations: thread owns (batch b_, hidden col gcol) ----
        if (tid < 256) {
            const int m2 = b_ >> 4, rD = b_ & 15;
            float v0 = 0.f, v1 = 0.f, v2 = 0.f, v3 = 0.f;
            #pragma unroll
            for (int q = 0; q < 4; ++q) {
                v0 += scr[q * 2 + m2][0][rD][col_];       // gate i
                v1 += scr[q * 2 + m2][0][rD][8 + col_];   // gate f
                v2 += scr[q * 2 + m2][1][rD][col_];       // gate g
                v3 += scr[q * 2 + m2][1][rD][8 + col_];   // gate o
            }
            const float ig = 1.f / (1.f + __expf(-(v0 + bias0)));
            const float fg = 1.f / (1.f + __expf(-(v1 + bias1)));
            const float gg = tanhf(v2 + bias2);
            const float og = 1.f / (1.f + __expf(-(v3 + bias3)));
            const float cc = fg * c_s[b_][col_] + ig * gg;
            const float hh = og * tanhf(cc);
            c_s[b_][col_] = cc;

            st_h[b_][col_] = (_Float16)hh;
            if (layer == 0) st_y[b_][col_] = (_Float16)(hh * mi_reg);
            else            st_o[b_][col_] = hh;

            if (s == T_STEPS - 1) {
                const size_t base = (size_t)T_STEPS * BATCH * HID;
                out[base + ((size_t)layer * BATCH + b_) * HID + gcol] = hh;
                out[base + (size_t)2 * BATCH * HID + ((size_t)layer * BATCH + b_) * HID + gcol] = cc;
            }
        }
        __syncthreads();

        // ---- producer tails (pollers, waves 0-3, go straight to next poll) ----
        if (layer == 0) {
            if (wid >= 4) {
                if (tid >= 448 && tid < 480) {
                    // wave 7 lower half: coherent stores -> ack -> flag
                    const int sl = tid - 448;
                    st_coh16(&h0b[((s + 1) & 1) * (BATCH * HID) + sl * HID + wgl * 8],
                             *(const half8*)st_h[sl]);
                    st_coh16(&y0m[((size_t)s * BATCH + sl) * HID + wgl * 8],
                             *(const half8*)st_y[sl]);
                    asm volatile("s_waitcnt vmcnt(0)" ::: "memory");
                    if (tid == 448)
                        __hip_atomic_store(flag0 + wgl * 32, (unsigned)(s + 1),
                                           __ATOMIC_RELAXED, __HIP_MEMORY_SCOPE_AGENT);
                }
                // x prefetch for s+1 (wave 7: AFTER the flag, so the ack above
                // never waits on HBM prefetch traffic)
                if (kq < 2 && s + 1 < T_STEPS) {
                    const float* xp = x + ((size_t)(s + 1) * BATCH + bb) * HID + kq * 512 + ko;
                    #pragma unroll
                    for (int kk = 0; kk < 16; ++kk) aF[kk] = cvt8(xp + kk * 32);
                }
            }
        } else {
            if (ot >= 0) {
                out[((size_t)s * BATCH + b2) * HID + gcol2] = st_o[b2][c2] * mo_reg;
                if (tid >= 448 && tid < 480) {
                    const int sl = tid - 448;
                    st_coh16(&h1b[((s + 1) & 1) * (BATCH * HID) + sl * HID + wgl * 8],
                             *(const half8*)st_h[sl]);
                    asm volatile("s_waitcnt vmcnt(0)" ::: "memory");
                    if (tid == 448)
                        __hip_atomic_store(flag1 + wgl * 32, (unsigned)(s + 1),
                                           __ATOMIC_RELAXED, __HIP_MEMORY_SCOPE_AGENT);
                }
                if (s + 1 < T_STEPS)
                    mo_reg = mo[((size_t)(s + 1) * BATCH + b2) * HID + gcol2];
            }
        }
    }
}

extern "C" void kernel_launch(void* const* d_in, const int* in_sizes, int n_in,
                              void* d_out, int out_size, void* d_ws, size_t ws_size,
                              hipStream_t stream) {
    const float* x   = (const float*)d_in[0];
    const float* h0  = (const float*)d_in[1];
    const float* c0  = (const float*)d_in[2];
    const float* Wih = (const float*)d_in[3];
    const float* Whh = (const float*)d_in[4];
    const float* bih = (const float*)d_in[5];
    const float* bhh = (const float*)d_in[6];
    const float* mi  = (const float*)d_in[7];
    const float* mo  = (const float*)d_in[8];
    float* out = (float*)d_out;

    char* w = (char*)d_ws;
    _Float16* y0m   = (_Float16*)w;                                // 13,107,200 B
    _Float16* h0b   = (_Float16*)(w + 13107200);                   //   131,072 B (2 slots)
    _Float16* h1b   = (_Float16*)(w + 13107200 + 131072);          //   131,072 B
    unsigned* flag0 = (unsigned*)(w + 13107200 + 262144);          //    16,384 B
    unsigned* flag1 = (unsigned*)(w + 13107200 + 262144 + 16384);  //    16,384 B

    hipLaunchKernelGGL(init_k, dim3(128), dim3(256), 0, stream,
                       h0, h0b, h1b, flag0, flag1);

    void* args[] = {(void*)&x, (void*)&c0, (void*)&Wih, (void*)&Whh,
                    (void*)&bih, (void*)&bhh, (void*)&mi, (void*)&mo,
                    (void*)&out, (void*)&y0m, (void*)&h0b, (void*)&h1b,
                    (void*)&flag0, (void*)&flag1};
    hipLaunchCooperativeKernel((void*)lstm_main, dim3(NWG), dim3(NTHR),
                               args, 0, stream);
}

// Round 7
// 2016.111 us; speedup vs baseline: 1.0763x; 1.0763x over previous
//
#include <hip/hip_runtime.h>

#define T_STEPS 200
#define BATCH   32
#define HID     1024
#define NWG     256
#define NTHR    512

typedef _Float16 half8 __attribute__((ext_vector_type(8)));
typedef float    f32x4 __attribute__((ext_vector_type(4)));

// Producer-side coherent (agent-scope, cache-bypassing) 16B store from two
// relaxed 8B atomics: write-through to LLC, never dirty in L2.
__device__ __forceinline__ void st_coh16(_Float16* p, half8 v) {
    union { half8 h; unsigned long long u[2]; } r; r.h = v;
    unsigned long long* q = (unsigned long long*)p;
    __hip_atomic_store(q,     r.u[0], __ATOMIC_RELAXED, __HIP_MEMORY_SCOPE_AGENT);
    __hip_atomic_store(q + 1, r.u[1], __ATOMIC_RELAXED, __HIP_MEMORY_SCOPE_AGENT);
}

__device__ __forceinline__ half8 cvt8(const float* p) {
    f32x4 lo = *(const f32x4*)p;
    f32x4 hi = *(const f32x4*)(p + 4);
    half8 a;
    a[0] = (_Float16)lo[0]; a[1] = (_Float16)lo[1];
    a[2] = (_Float16)lo[2]; a[3] = (_Float16)lo[3];
    a[4] = (_Float16)hi[0]; a[5] = (_Float16)hi[1];
    a[6] = (_Float16)hi[2]; a[7] = (_Float16)hi[3];
    return a;
}

__global__ void init_k(const float* __restrict__ h0,
                       _Float16* __restrict__ h0b, _Float16* __restrict__ h1b,
                       unsigned* __restrict__ flag0, unsigned* __restrict__ flag1) {
    int i = blockIdx.x * blockDim.x + threadIdx.x;
    if (i < BATCH * HID) {
        h0b[i] = (_Float16)h0[i];                 // layer 0 initial h -> slot 0
        h1b[i] = (_Float16)h0[BATCH * HID + i];   // layer 1 initial h -> slot 0
    }
    if (blockIdx.x == 0) {
        if (threadIdx.x < 128)      flag0[threadIdx.x * 32] = 0;
        else if (threadIdx.x < 256) flag1[(threadIdx.x - 128) * 32] = 0;
    }
}

// Self-timed dataflow LSTM, NO global barrier (R6 structure). NEW (R7):
// consumers read the exchanged h/y0m with PLAIN CACHED loads; coherence via
// one agent-scope acquire fence (buffer_inv: L1+L2 invalidate) per WG per
// tick, executed after the flag-wait. Producers still store write-through to
// LLC (agent-scope atomics) + vmcnt ack + flag, so all exchange data is at
// the LLC before any consumer's post-inv L2 fill. This converts the 24 MB/tick
// 8B-granule LLC fan-out (~3.1M requests) into ~12K 128B line fills shared
// through each XCD's L2.
__global__ __launch_bounds__(NTHR, 2) void lstm_main(
    const float* __restrict__ x, const float* __restrict__ c0,
    const float* __restrict__ Wih, const float* __restrict__ Whh,
    const float* __restrict__ bih, const float* __restrict__ bhh,
    const float* __restrict__ mi, const float* __restrict__ mo,
    float* __restrict__ out,
    _Float16* __restrict__ y0m, _Float16* __restrict__ h0b,
    _Float16* __restrict__ h1b, unsigned* __restrict__ flag0,
    unsigned* __restrict__ flag1)
{
    __shared__ _Float16 W_s[32 * 2048];     // 128 KB
    __shared__ float scr[8][2][16][17];     // per-(kq,m) partial gate tiles
    __shared__ float c_s[BATCH][8];         // persistent cell state (f32)
    __shared__ alignas(16) _Float16 st_h[BATCH][8];  // staged h for wave-7 stores
    __shared__ alignas(16) _Float16 st_y[BATCH][8];  // staged y0*mask (layer 0)
    __shared__ float st_o[BATCH][8];        // staged h for out-stores (layer 1)

    const int bid   = blockIdx.x;
    const int layer = bid >> 7;
    const int wgl   = bid & 127;
    const int tid   = threadIdx.x;

    // ---- one-time: stage this WG's weight slice into LDS (f16, swizzled) ----
    const float* WihL = Wih + (size_t)layer * 4 * HID * HID;
    const float* WhhL = Whh + (size_t)layer * 4 * HID * HID;
    for (int idx = tid; idx < 32 * 2048; idx += NTHR) {
        int r = idx >> 11, k = idx & 2047;             // r: local gate-row
        int grow = (r >> 3) * HID + wgl * 8 + (r & 7); // global row in [4H]
        float v = (k < HID) ? WihL[(size_t)grow * HID + k]
                            : WhhL[(size_t)grow * HID + (k - HID)];
        W_s[idx ^ ((r & 7) << 3)] = (_Float16)v;       // XOR-swizzle (16B granules)
    }

    float bias0 = 0.f, bias1 = 0.f, bias2 = 0.f, bias3 = 0.f;
    int b_ = 0, col_ = 0, gcol = 0;
    if (tid < 256) {
        b_ = tid >> 3; col_ = tid & 7; gcol = wgl * 8 + col_;
        bias0 = bih[layer * 4096 + gcol]           + bhh[layer * 4096 + gcol];
        bias1 = bih[layer * 4096 + HID + gcol]     + bhh[layer * 4096 + HID + gcol];
        bias2 = bih[layer * 4096 + 2 * HID + gcol] + bhh[layer * 4096 + 2 * HID + gcol];
        bias3 = bih[layer * 4096 + 3 * HID + gcol] + bhh[layer * 4096 + 3 * HID + gcol];
        c_s[b_][col_] = c0[((size_t)layer * BATCH + b_) * HID + gcol];
    }
    // out-store / mask threads (waves 4-7): own (b2, c2)
    const int ot = tid - 256;
    const int b2 = (ot >= 0) ? (ot >> 3) : 0, c2 = (ot >= 0) ? (ot & 7) : 0;
    const int gcol2 = wgl * 8 + c2;
    __syncthreads();

    const int lane = tid & 63, wid = tid >> 6;
    // layer 0: waves 0-3 own the h-half (kq 2,3); waves 4-7 own the x-half
    // (kq 0,1, register-prefetched). layer 1: plain kq = wid>>1.
    int kq;
    if (layer == 0) kq = (wid < 4) ? (2 + (wid >> 1)) : ((wid - 4) >> 1);
    else            kq = wid >> 1;
    const int mm   = wid & 1;
    const int srow = kq * 2 + mm;          // scr slot (logical, not wid)
    const int row = lane & 15, bb = mm * 16 + row, ko = (lane >> 4) * 8;

    // ---- prefetched pure-t state ----
    half8 aF[16];
    float mi_reg = 0.f, mo_reg = 0.f;
    if (layer == 0 && kq < 2) {
        const float* xp = x + (size_t)bb * HID + kq * 512 + ko;   // s = 0
        #pragma unroll
        for (int kk = 0; kk < 16; ++kk) aF[kk] = cvt8(xp + kk * 32);
    }
    if (layer == 1 && ot >= 0) mo_reg = mo[(size_t)b2 * HID + gcol2];  // s = 0

    for (int s = 0; s < T_STEPS; ++s) {
        // ---- dataflow wait (lane-private spins; no pending stores here) ----
        if (layer == 0) {
            if (tid < 128) {
                const unsigned* f = flag0 + tid * 32;
                const unsigned tgt = (unsigned)s;
                while (__hip_atomic_load(f, __ATOMIC_RELAXED,
                                         __HIP_MEMORY_SCOPE_AGENT) < tgt) {}
            }
        } else {
            if (tid < 128) {
                const unsigned* f = flag0 + tid * 32;
                const unsigned tgt = (unsigned)(s + 1);
                while (__hip_atomic_load(f, __ATOMIC_RELAXED,
                                         __HIP_MEMORY_SCOPE_AGENT) < tgt) {}
            } else if (tid < 256) {
                const unsigned* f = flag1 + (tid - 128) * 32;
                const unsigned tgt = (unsigned)s;
                while (__hip_atomic_load(f, __ATOMIC_RELAXED,
                                         __HIP_MEMORY_SCOPE_AGENT) < tgt) {}
            }
        }
        asm volatile("" ::: "memory");
        __syncthreads();
        // ---- acquire: invalidate L1+L2 so plain loads see the LLC data ----
        if (tid == 0) __builtin_amdgcn_fence(__ATOMIC_ACQUIRE, "agent");
        __syncthreads();

        // ---- mask load for this step (hidden under MFMA phase) ----
        if (layer == 0 && tid < 256)
            mi_reg = mi[((size_t)s * BATCH + b_) * HID + gcol];

        // ---- dependent A fragments: PLAIN CACHED loads (L2-shared fills) ----
        if (layer == 0) {
            if (kq >= 2) {
                const _Float16* hp = h0b + (s & 1) * (BATCH * HID)
                                   + bb * HID + (kq - 2) * 512 + ko;
                #pragma unroll
                for (int kk = 0; kk < 16; ++kk)
                    aF[kk] = *(const half8*)(hp + kk * 32);
            }
        } else {
            if (kq < 2) {
                const _Float16* yp = y0m + ((size_t)s * BATCH + bb) * HID + kq * 512 + ko;
                #pragma unroll
                for (int kk = 0; kk < 16; ++kk)
                    aF[kk] = *(const half8*)(yp + kk * 32);
            } else {
                const _Float16* hp = h1b + (s & 1) * (BATCH * HID)
                                   + bb * HID + (kq - 2) * 512 + ko;
                #pragma unroll
                for (int kk = 0; kk < 16; ++kk)
                    aF[kk] = *(const half8*)(hp + kk * 32);
            }
        }

        // ---- MFMA: D[batch 16][gaterow 16] x2 subtiles over K=512 ----
        f32x4 acc0 = {0.f, 0.f, 0.f, 0.f}, acc1 = {0.f, 0.f, 0.f, 0.f};
        #pragma unroll
        for (int kk = 0; kk < 16; ++kk) {
            const int k  = kq * 512 + kk * 32 + ko;
            const int r1 = 16 + row;
            const half8 bB0 = *(const half8*)&W_s[(row * 2048 + k) ^ ((row & 7) << 3)];
            const half8 bB1 = *(const half8*)&W_s[(r1 * 2048 + k) ^ ((r1 & 7) << 3)];
            acc0 = __builtin_amdgcn_mfma_f32_16x16x32_f16(aF[kk], bB0, acc0, 0, 0, 0);
            acc1 = __builtin_amdgcn_mfma_f32_16x16x32_f16(aF[kk], bB1, acc1, 0, 0, 0);
        }
        #pragma unroll
        for (int j = 0; j < 4; ++j) {
            scr[srow][0][(lane >> 4) * 4 + j][row] = acc0[j];
            scr[srow][1][(lane >> 4) * 4 + j][row] = acc1[j];
        }
        __syncthreads();

        // ---- activations: thread owns (batch b_, hidden col gcol) ----
        if (tid < 256) {
            const int m2 = b_ >> 4, rD = b_ & 15;
            float v0 = 0.f, v1 = 0.f, v2 = 0.f, v3 = 0.f;
            #pragma unroll
            for (int q = 0; q < 4; ++q) {
                v0 += scr[q * 2 + m2][0][rD][col_];       // gate i
                v1 += scr[q * 2 + m2][0][rD][8 + col_];   // gate f
                v2 += scr[q * 2 + m2][1][rD][col_];       // gate g
                v3 += scr[q * 2 + m2][1][rD][8 + col_];   // gate o
            }
            const float ig = 1.f / (1.f + __expf(-(v0 + bias0)));
            const float fg = 1.f / (1.f + __expf(-(v1 + bias1)));
            const float gg = tanhf(v2 + bias2);
            const float og = 1.f / (1.f + __expf(-(v3 + bias3)));
            const float cc = fg * c_s[b_][col_] + ig * gg;
            const float hh = og * tanhf(cc);
            c_s[b_][col_] = cc;

            st_h[b_][col_] = (_Float16)hh;
            if (layer == 0) st_y[b_][col_] = (_Float16)(hh * mi_reg);
            else            st_o[b_][col_] = hh;

            if (s == T_STEPS - 1) {
                const size_t base = (size_t)T_STEPS * BATCH * HID;
                // agent-scope stores: write-through, never dirty in L2 (inv-safe)
                __hip_atomic_store(&out[base + ((size_t)layer * BATCH + b_) * HID + gcol],
                                   hh, __ATOMIC_RELAXED, __HIP_MEMORY_SCOPE_AGENT);
                __hip_atomic_store(&out[base + (size_t)2 * BATCH * HID
                                        + ((size_t)layer * BATCH + b_) * HID + gcol],
                                   cc, __ATOMIC_RELAXED, __HIP_MEMORY_SCOPE_AGENT);
            }
        }
        __syncthreads();

        // ---- producer tails ----
        if (layer == 0) {
            if (wid >= 4) {
                if (tid >= 448 && tid < 480) {
                    // wave 7 lower half: coherent stores -> ack -> flag
                    const int sl = tid - 448;
                    st_coh16(&h0b[((s + 1) & 1) * (BATCH * HID) + sl * HID + wgl * 8],
                             *(const half8*)st_h[sl]);
                    st_coh16(&y0m[((size_t)s * BATCH + sl) * HID + wgl * 8],
                             *(const half8*)st_y[sl]);
                    asm volatile("s_waitcnt vmcnt(0)" ::: "memory");
                    if (tid == 448)
                        __hip_atomic_store(flag0 + wgl * 32, (unsigned)(s + 1),
                                           __ATOMIC_RELAXED, __HIP_MEMORY_SCOPE_AGENT);
                }
                // x prefetch for s+1 (after the flag: ack never waits on HBM)
                if (kq < 2 && s + 1 < T_STEPS) {
                    const float* xp = x + ((size_t)(s + 1) * BATCH + bb) * HID + kq * 512 + ko;
                    #pragma unroll
                    for (int kk = 0; kk < 16; ++kk) aF[kk] = cvt8(xp + kk * 32);
                }
            }
        } else {
            if (ot >= 0) {
                // agent-scope out store: write-through (inv-safe)
                __hip_atomic_store(&out[((size_t)s * BATCH + b2) * HID + gcol2],
                                   st_o[b2][c2] * mo_reg,
                                   __ATOMIC_RELAXED, __HIP_MEMORY_SCOPE_AGENT);
                if (tid >= 448 && tid < 480) {
                    const int sl = tid - 448;
                    st_coh16(&h1b[((s + 1) & 1) * (BATCH * HID) + sl * HID + wgl * 8],
                             *(const half8*)st_h[sl]);
                    asm volatile("s_waitcnt vmcnt(0)" ::: "memory");
                    if (tid == 448)
                        __hip_atomic_store(flag1 + wgl * 32, (unsigned)(s + 1),
                                           __ATOMIC_RELAXED, __HIP_MEMORY_SCOPE_AGENT);
                }
                if (s + 1 < T_STEPS)
                    mo_reg = mo[((size_t)(s + 1) * BATCH + b2) * HID + gcol2];
            }
        }
    }
}

extern "C" void kernel_launch(void* const* d_in, const int* in_sizes, int n_in,
                              void* d_out, int out_size, void* d_ws, size_t ws_size,
                              hipStream_t stream) {
    const float* x   = (const float*)d_in[0];
    const float* h0  = (const float*)d_in[1];
    const float* c0  = (const float*)d_in[2];
    const float* Wih = (const float*)d_in[3];
    const float* Whh = (const float*)d_in[4];
    const float* bih = (const float*)d_in[5];
    const float* bhh = (const float*)d_in[6];
    const float* mi  = (const float*)d_in[7];
    const float* mo  = (const float*)d_in[8];
    float* out = (float*)d_out;

    char* w = (char*)d_ws;
    _Float16* y0m   = (_Float16*)w;                                // 13,107,200 B
    _Float16* h0b   = (_Float16*)(w + 13107200);                   //   131,072 B (2 slots)
    _Float16* h1b   = (_Float16*)(w + 13107200 + 131072);          //   131,072 B
    unsigned* flag0 = (unsigned*)(w + 13107200 + 262144);          //    16,384 B
    unsigned* flag1 = (unsigned*)(w + 13107200 + 262144 + 16384);  //    16,384 B

    hipLaunchKernelGGL(init_k, dim3(128), dim3(256), 0, stream,
                       h0, h0b, h1b, flag0, flag1);

    void* args[] = {(void*)&x, (void*)&c0, (void*)&Wih, (void*)&Whh,
                    (void*)&bih, (void*)&bhh, (void*)&mi, (void*)&mo,
                    (void*)&out, (void*)&y0m, (void*)&h0b, (void*)&h1b,
                    (void*)&flag0, (void*)&flag1};
    hipLaunchCooperativeKernel((void*)lstm_main, dim3(NWG), dim3(NTHR),
                               args, 0, stream);
}